// Round 10
// baseline (306.729 us; speedup 1.0000x reference)
//
#include <hip/hip_runtime.h>
#include <math.h>

typedef __bf16 bf16x8 __attribute__((ext_vector_type(8)));
typedef float f32x4 __attribute__((ext_vector_type(4)));
typedef short short4v __attribute__((ext_vector_type(4)));
typedef short short8v __attribute__((ext_vector_type(8)));

#define NB 4
#define NT 48
#define NV 32
#define ND 512
#define NH 8
#define NN 1536   // T*V
#define NBN 6144  // B*N
#define L2E 1.44269504f

#define GLOAD_LDS(g, l) \
    __builtin_amdgcn_global_load_lds( \
        (const __attribute__((address_space(1))) void*)(g), \
        (__attribute__((address_space(3))) void*)(l), 16, 0, 0)

// ---------------------------------------------------------------------------
// prep: fused conv_h (blocks 0..1535) + weight transpose (1536..1791) +
// kx obs/zero segments (1792..2175).  log2e folded into Wq/bq scale.
// (R6 form, unchanged.)
// ---------------------------------------------------------------------------
__global__ __launch_bounds__(256) void prep(
    const float* __restrict__ h, const float* __restrict__ obs,
    const float* __restrict__ Wq, const float* __restrict__ Wk,
    const float* __restrict__ Wv, const float* __restrict__ Wo,
    const float* __restrict__ bq, const float* __restrict__ bk,
    const float* __restrict__ bv,
    const float* __restrict__ Wok, const float* __restrict__ bok,
    __bf16* __restrict__ h_bf, __bf16* __restrict__ WcatT,
    __bf16* __restrict__ WoT, float* __restrict__ biascat,
    __bf16* __restrict__ kx)
{
    __shared__ float ts[64][68];
    const int tid = threadIdx.x;
    const int bx = blockIdx.x;
    if (bx < 1536) {
        int t = bx * 256 + tid;
        const float4* src = (const float4*)h + (size_t)t * 2;
        float4 a = src[0], b = src[1];
        __bf16 r[8] = {(__bf16)a.x, (__bf16)a.y, (__bf16)a.z, (__bf16)a.w,
                       (__bf16)b.x, (__bf16)b.y, (__bf16)b.z, (__bf16)b.w};
        *(uint4*)(h_bf + (size_t)t * 8) = *(uint4*)r;
    } else if (bx < 1792) {
        int bw = bx - 1536;
        const int p = bw >> 6, tile = bw & 63;
        const int k0 = (tile >> 3) * 64, c0 = (tile & 7) * 64;
        const float* W = (p == 0) ? Wq : (p == 1) ? Wk : (p == 2) ? Wv : Wo;
        const float scale = (p == 0) ? 0.125f * L2E : 1.0f;
        #pragma unroll
        for (int i = 0; i < 4; i++) {
            int r = (tid >> 4) + i * 16;
            float4 v = *(const float4*)(W + (size_t)(k0 + r) * 512 + c0 + (tid & 15) * 4);
            *(float4*)&ts[r][(tid & 15) * 4] = v;
        }
        __syncthreads();
        __bf16 tmp[16];
        #pragma unroll
        for (int j = 0; j < 16; j++)
            tmp[j] = (__bf16)(ts[(tid & 3) * 16 + j][tid >> 2] * scale);
        int crow = c0 + (tid >> 2);
        __bf16* dst = (p < 3)
            ? WcatT + ((size_t)(p * 512 + crow)) * 512 + k0 + (tid & 3) * 16
            : WoT   + ((size_t)crow) * 512 + k0 + (tid & 3) * 16;
        *(uint4*)dst = *(uint4*)tmp;
        *(uint4*)(dst + 8) = *(uint4*)(tmp + 8);
        if (p < 3 && k0 == 0 && tid < 64) {
            const float* bb = (p == 0) ? bq : (p == 1) ? bk : bv;
            biascat[p * 512 + c0 + tid] = bb[c0 + tid] * scale;
        }
    } else {
        int t = (bx - 1792) * 256 + tid;               // 0..98303
        int row = t >> 1, half = t & 1;                // row = bh*1536 + n
        __bf16* dst = kx + (size_t)row * 96 + 64 + half * 16;
        if (half == 0) {
            int bh = row / NN, n = row - bh * NN;
            int b = bh >> 3, hh = bh & 7;
            size_t bn = (size_t)b * NN + n;
            float o0 = obs[bn * 2], o1 = obs[bn * 2 + 1];
            int f = hh * 16;
            __bf16 tmp[16];
            #pragma unroll
            for (int j = 0; j < 16; j++)
                tmp[j] = (__bf16)(o0 * Wok[f + j] + o1 * Wok[128 + f + j] + bok[f + j]);
            *(uint4*)dst       = *(uint4*)tmp;
            *(uint4*)(dst + 8) = *(uint4*)(tmp + 8);
        } else {
            uint4 z = {0, 0, 0, 0};
            *(uint4*)dst       = z;
            *(uint4*)(dst + 8) = z;
        }
    }
}

// ---------------------------------------------------------------------------
// bf16 MFMA GEMM — software-pipelined (R1, kept).  K-tile epilogue -> R3
// row-major kx.  V-tile epilogue -> vt4 packed-pair fragment layout
// (R6-verified).  Unchanged.
// ---------------------------------------------------------------------------
template<int TM, bool BF16OUT>
__global__ __launch_bounds__(256) void gemm_mfma(
    const __bf16* __restrict__ A, const __bf16* __restrict__ Bt,
    const float* __restrict__ bias, float* __restrict__ Cf,
    __bf16* __restrict__ qarr, __bf16* __restrict__ kx,
    __bf16* __restrict__ vt)
{
    constexpr int MT = TM / 32;
    __shared__ __align__(16) char smem[34816];
    char* const As0 = smem;
    char* const As1 = smem + TM * 64;
    char* const Bs0 = smem + TM * 128;
    char* const Bs1 = smem + TM * 128 + 8192;
    const int tid = threadIdx.x;
    const int w = tid >> 6, lane = tid & 63;
    const int quad = lane >> 4, l16 = lane & 15;
    const int wm = w >> 1, wn = w & 1;
    const int n0 = blockIdx.x * 128, m0 = blockIdx.y * TM;

    const int sm = tid >> 2;
    const int sk = ((tid & 3) ^ ((sm >> 1) & 3)) * 8;
    const __bf16* aptr = A  + (size_t)(m0 + sm) * 512 + sk;
    const __bf16* bptr = Bt + (size_t)(n0 + sm) * 512 + sk;

    f32x4 zero4 = {0.f, 0.f, 0.f, 0.f};
    f32x4 acc[MT][4];
    #pragma unroll
    for (int i = 0; i < MT; i++)
        #pragma unroll
        for (int j = 0; j < 4; j++) acc[i][j] = zero4;

    auto STAGE = [&](char* dA, char* dB, int kt) {
        GLOAD_LDS(aptr + kt, dA + tid * 16);
        if (TM == 128) GLOAD_LDS(aptr + 64 * 512 + kt, dA + 4096 + tid * 16);
        GLOAD_LDS(bptr + kt, dB + tid * 16);
        GLOAD_LDS(bptr + 64 * 512 + kt, dB + 4096 + tid * 16);
    };
    auto COMPUTE = [&](const char* Asb, const char* Bsb) {
        bf16x8 af[MT], bfr[4];
        #pragma unroll
        for (int mt = 0; mt < MT; mt++) {
            int rr = wm * (TM / 2) + mt * 16 + l16;
            af[mt] = *(const bf16x8*)(Asb + rr * 64 + (quad ^ ((rr >> 1) & 3)) * 16);
        }
        #pragma unroll
        for (int nt = 0; nt < 4; nt++) {
            int rr = wn * 64 + nt * 16 + l16;
            bfr[nt] = *(const bf16x8*)(Bsb + rr * 64 + (quad ^ ((rr >> 1) & 3)) * 16);
        }
        #pragma unroll
        for (int mt = 0; mt < MT; mt++)
            #pragma unroll
            for (int nt = 0; nt < 4; nt++)
                acc[mt][nt] = __builtin_amdgcn_mfma_f32_16x16x32_bf16(
                    af[mt], bfr[nt], acc[mt][nt], 0, 0, 0);
    };

    STAGE(As0, Bs0, 0);
    asm volatile("s_waitcnt vmcnt(0)" ::: "memory");
    __builtin_amdgcn_s_barrier();
    for (int kt = 0; kt < 512; kt += 64) {
        STAGE(As1, Bs1, kt + 32);          // always valid: last is kt=448 -> 480
        COMPUTE(As0, Bs0);
        asm volatile("s_waitcnt vmcnt(0)" ::: "memory");
        __builtin_amdgcn_s_barrier();
        if (kt + 64 < 512) STAGE(As0, Bs0, kt + 64);
        COMPUTE(As1, Bs1);
        asm volatile("s_waitcnt vmcnt(0)" ::: "memory");
        __builtin_amdgcn_s_barrier();
    }

    __syncthreads();   // frag reads done; smem becomes C-stage
    if (BF16OUT) {
        if (n0 >= 1024) {
            // ---- V tile: stage TRANSPOSED (CsT[col][136 rows]), write vt4 ----
            __bf16* CsT = (__bf16*)smem;
            #pragma unroll
            for (int nt = 0; nt < 4; nt++) {
                int cl = wn * 64 + nt * 16 + l16;
                float bia = bias[n0 + cl];
                #pragma unroll
                for (int mt = 0; mt < MT; mt++) {
                    int rl0 = wm * (TM / 2) + mt * 16 + quad * 4;
                    __bf16 pk[4];
                    #pragma unroll
                    for (int r = 0; r < 4; r++)
                        pk[r] = (__bf16)(acc[mt][nt][r] + bia);
                    *(uint2*)&CsT[cl * 136 + rl0] = *(uint2*)pk;
                }
            }
            __syncthreads();
            int cl = tid >> 1, half = tid & 1;
            int f0 = (n0 + cl) & 511;
            int hh = f0 >> 6, d = f0 & 63;
            int dt = d >> 4, l16v = d & 15;
            int bidx = m0 / NN, nm = m0 - bidx * NN;
            int bh = bidx * 8 + hh;
            int mtv = (nm >> 6) + half;
            #pragma unroll
            for (int j = 0; j < 8; j++) {
                uint4 v = *(uint4*)&CsT[cl * 136 + half * 64 + j * 8];
                __bf16* pp = (__bf16*)&v;
                int q0 = (j & 1) * 2;
                size_t fo = ((size_t)(bh * 24 + mtv) * 8 + (j >> 1) * 2 + (dt >> 1)) * 512
                            + (dt & 1) * 4 + l16v * 8;
                *(uint2*)(vt + fo + q0 * 128)       = *(uint2*)&pp[0];
                *(uint2*)(vt + fo + (q0 + 1) * 128) = *(uint2*)&pp[4];
            }
        } else {
            // ---- Q/K tile: row-major stage, routed stores (R3 form) ----
            __bf16* Cs = (__bf16*)smem;               // [TM][132]
            #pragma unroll
            for (int mt = 0; mt < MT; mt++)
                #pragma unroll
                for (int nt = 0; nt < 4; nt++) {
                    int cl = wn * 64 + nt * 16 + l16;
                    float bia = bias[n0 + cl];
                    #pragma unroll
                    for (int r = 0; r < 4; r++) {
                        int rl = wm * (TM / 2) + mt * 16 + quad * 4 + r;
                        Cs[rl * 132 + cl] = (__bf16)(acc[mt][nt][r] + bia);
                    }
                }
            __syncthreads();
            int rl = tid >> 1, hb = tid & 1;
            int grow = m0 + rl;
            int col0 = n0 + hb * 64;
            int p = col0 >> 9, f0 = col0 & 511, hh = f0 >> 6;
            int bidx = grow / NN, n = grow - bidx * NN;
            __bf16* dst = (p == 0) ? qarr + (size_t)grow * 512 + f0
                                   : kx + ((size_t)(bidx * 8 + hh) * NN + n) * 96;
            #pragma unroll
            for (int j = 0; j < 8; j++) {
                uint2 lo = *(uint2*)&Cs[rl * 132 + hb * 64 + j * 8];
                uint2 hi = *(uint2*)&Cs[rl * 132 + hb * 64 + j * 8 + 4];
                uint4 v = {lo.x, lo.y, hi.x, hi.y};
                *(uint4*)(dst + j * 8) = v;
            }
        }
    } else {
        float* Csf = (float*)smem;                // [64][132]
        #pragma unroll
        for (int mt = 0; mt < MT; mt++)
            #pragma unroll
            for (int nt = 0; nt < 4; nt++) {
                int cl = wn * 64 + nt * 16 + l16;
                float bia = bias[n0 + cl];
                #pragma unroll
                for (int r = 0; r < 4; r++) {
                    int rl = wm * (TM / 2) + mt * 16 + quad * 4 + r;
                    Csf[rl * 132 + cl] = acc[mt][nt][r] + bia;
                }
            }
        __syncthreads();
        int rl = tid >> 2, q4 = tid & 3;
        float* dst = Cf + (size_t)(m0 + rl) * 512 + n0 + q4 * 32;
        #pragma unroll
        for (int j = 0; j < 8; j++) {
            uint4 v = *(uint4*)&Csf[rl * 132 + q4 * 32 + j * 4];
            *(uint4*)(dst + j * 4) = v;
        }
    }
}

// ---------------------------------------------------------------------------
// Flash attention, n-split, INTRA-BLOCK KV-SPLIT (R10): grid (32,24), 512
// threads.  Waves 0-3 (z=0) process K-tiles 0..11, waves 4-7 (z=1) tiles
// 12..23, lockstep under shared barriers; each half has its own 16 KB Ks.
// Partials combined in LDS at block end (reuse Ks half 1), output bf16
// directly — no HBM intermediate (R8/R9's 50 MB f32 stream evicted K/V
// reuse from L2: FETCH 11->330 MB).  24 waves/CU (3 blocks x 8 waves), per-
// wave chain 12 tiles.  Register-P PV + lp-via-ones-MFMA kept (verified).
// ---------------------------------------------------------------------------
__global__ __launch_bounds__(512, 6) void attn_mfma(
    const __bf16* __restrict__ qarr, const __bf16* __restrict__ kx,
    const __bf16* __restrict__ vt, const float* __restrict__ obs,
    const float* __restrict__ Woq, const float* __restrict__ boq,
    const float* __restrict__ varb, const float* __restrict__ rtb,
    __bf16* __restrict__ aout)
{
    __shared__ __align__(16) __bf16 Ks[2][64][128];  // per-half K tile, XOR-swz
    __shared__ float rts[96];
    __shared__ float lpx[64];

    const int tid = threadIdx.x;
    const int w = tid >> 6;            // 0..7
    const int z = w >> 2;              // half: 0 or 1
    const int wq = w & 3;              // wave-within-half
    const int lane = tid & 63;
    const int quad = lane >> 4, l16 = lane & 15;
    const int bh = blockIdx.x, qt = blockIdx.y;   // XCD-locality swizzle
    const int b = bh >> 3, h = bh & 7;
    const int n0 = qt * 64;
    const int mt0 = z * 12, mt1 = mt0 + 12;

    if (tid < 95) rts[tid] = rtb[h * 95 + tid] * L2E;

    // K staging map (R3-proven); each half stages into its own Ks[z].
    // Within a half, 4 waves cooperate exactly as the 256-thread version
    // (tid4 = tid & 255 plays the old tid role).
    const int tid4 = tid & 255;
    const int ck = (tid4 & 15) ^ ((tid4 >> 4) & 7);
    const __bf16* kbase = kx + (size_t)bh * NN * 96 + ck * 8;
    auto STAGE_K = [&](int m0s) {
        #pragma unroll
        for (int i = 0; i < 1; i++) {
            int row = (z ? 0 : 0);  (void)row;
        }
        // each thread issues ONE load per 16-row group; 4 groups total are
        // covered by the half's 256 threads exactly as before:
        int rowg = tid4 >> 4;          // 0..15
        #pragma unroll
        for (int i = 0; i < 4; i++) {
            int row = i * 16 + rowg;
            GLOAD_LDS(kbase + (size_t)(m0s + row) * 96,
                      (char*)Ks + z * 16384 + i * 4096 + tid4 * 16);
        }
    };
    STAGE_K(mt0 * 64);

    // V fragment base (vt4)
    const __bf16* vwb = vt + (size_t)bh * 24 * 4096 + lane * 8;

    // Q fragments (B-operand): lane l16 holds row n = wq*16+l16 (both halves
    // load the same rows — duplicated read, L2-hit)
    const int nl = wq * 16 + l16;
    const size_t qrow = (size_t)(b * NN + n0 + nl);
    bf16x8 bq_[3];
    bq_[0] = *(const bf16x8*)(qarr + qrow * 512 + h * 64 + quad * 8);
    bq_[1] = *(const bf16x8*)(qarr + qrow * 512 + h * 64 + 32 + quad * 8);
    {   // inline oq: logical k 64..95 -> oq[0..15] then zeros; 0.25*log2e folded
        uint4 a2u = {0u, 0u, 0u, 0u};
        if (quad < 2) {
            float o0 = obs[qrow * 2], o1 = obs[qrow * 2 + 1];
            int f = h * 16 + quad * 8;
            const float sc = 0.25f * L2E;
            __bf16 tmp[8];
            #pragma unroll
            for (int j = 0; j < 8; j++)
                tmp[j] = (__bf16)(sc * (o0 * Woq[f + j] + o1 * Woq[128 + f + j]
                                        + boq[f + j]));
            a2u = *(uint4*)tmp;
        }
        bq_[2] = *(bf16x8*)&a2u;
    }

    // var-bias: row (n&31) fixed per lane; m&31 = (ct&1)*16 + quad*4 + r
    const int rm = (wq & 1) * 16 + l16;
    float4 vbA = *(const float4*)(varb + h * 1024 + rm * 32 + quad * 4);
    float4 vbB = *(const float4*)(varb + h * 1024 + rm * 32 + 16 + quad * 4);
    float vA[4] = {vbA.x * L2E, vbA.y * L2E, vbA.z * L2E, vbA.w * L2E};
    float vB[4] = {vbB.x * L2E, vbB.y * L2E, vbB.z * L2E, vbB.w * L2E};
    const int tn = 2 * qt + (wq >> 1);

    // ones fragment for the lp MFMA
    union { __bf16 e[4]; short4v s; } one_u;
    #pragma unroll
    for (int j = 0; j < 4; j++) one_u.e[j] = (__bf16)1.0f;
    const short4v ones = one_u.s;

    f32x4 zero4 = {0.f, 0.f, 0.f, 0.f};
    f32x4 o_p[4];                     // [dt]: row d = dt*16+quad*4+r, col n=l16
    f32x4 lpa = zero4;
    #pragma unroll
    for (int i = 0; i < 4; i++) o_p[i] = zero4;

    asm volatile("s_waitcnt vmcnt(0) lgkmcnt(0)" ::: "memory");
    __builtin_amdgcn_s_barrier();     // tiles mt0 (both halves) staged + rts

    for (int mt = mt0; mt < mt1; mt++) {
        // V fragments (global->VGPR, consumed at PV; covered by QK)
        short8v v0[8];
        {
            const __bf16* vp = vwb + (size_t)mt * 4096;
            #pragma unroll
            for (int fi = 0; fi < 8; fi++)
                v0[fi] = *(const short8v*)(vp + fi * 512);
        }
        // ---- S^T = K.Q^T over K=96 (reads own half's Ks) ----
        f32x4 sc[4];
        __builtin_amdgcn_s_setprio(1);
        #pragma unroll
        for (int ct = 0; ct < 4; ct++) {
            f32x4 d = zero4;
            int row = ct * 16 + l16;
            #pragma unroll
            for (int ks = 0; ks < 3; ks++) {
                bf16x8 kf = *(const bf16x8*)((const char*)Ks + z * 16384
                                + row * 256 + (((ks * 4 + quad) ^ (row & 7)) * 16));
                d = __builtin_amdgcn_mfma_f32_16x16x32_bf16(kf, bq_[ks], d, 0, 0, 0);
            }
            sc[ct] = d;
        }
        __builtin_amdgcn_s_setprio(0);

        // all waves done reading their Ks -> safe to overwrite
        asm volatile("s_waitcnt lgkmcnt(0)" ::: "memory");
        __builtin_amdgcn_s_barrier();
        if (mt + 1 < mt1) STAGE_K((mt + 1) * 64);

        // ---- biases + exp2 -> P in registers ----
        float tb0 = rts[tn - 2 * mt + 47];
        float tb1 = rts[tn - 2 * mt + 46];
        short4v pf[4];
        #pragma unroll
        for (int ct = 0; ct < 4; ct++) {
            float tb = (ct & 2) ? tb1 : tb0;
            const float* vv = (ct & 1) ? vB : vA;
            union { __bf16 e[4]; short4v s; } pk;
            #pragma unroll
            for (int r = 0; r < 4; r++)
                pk.e[r] = (__bf16)exp2f(sc[ct][r] + tb + vv[r]);
            pf[ct] = pk.s;
        }

        // ---- O^T += V^T.P^T (16x16x16, register A/B) + lp ----
        __builtin_amdgcn_s_setprio(1);
        #pragma unroll
        for (int ct = 0; ct < 4; ct++) {
            lpa = __builtin_amdgcn_mfma_f32_16x16x16bf16_1k(ones, pf[ct], lpa, 0, 0, 0);
            #pragma unroll
            for (int dt = 0; dt < 4; dt++) {
                short8v v8 = v0[ct * 2 + (dt >> 1)];
                short4v va = (dt & 1)
                    ? __builtin_shufflevector(v8, v8, 4, 5, 6, 7)
                    : __builtin_shufflevector(v8, v8, 0, 1, 2, 3);
                o_p[dt] = __builtin_amdgcn_mfma_f32_16x16x16bf16_1k(
                    va, pf[ct], o_p[dt], 0, 0, 0);
            }
        }
        __builtin_amdgcn_s_setprio(0);

        // staged K landed everywhere
        asm volatile("s_waitcnt vmcnt(0)" ::: "memory");
        __builtin_amdgcn_s_barrier();
    }

    // ---- combine halves in LDS (reuse Ks), then normalize + store bf16 ----
    float* ox = (float*)Ks;           // 16 KB: [wq][dt][lane] f32x4
    if (z == 1) {
        #pragma unroll
        for (int dt = 0; dt < 4; dt++)
            *(f32x4*)(ox + ((wq * 4 + dt) * 64 + lane) * 4) = o_p[dt];
        if (quad == 0) lpx[nl] = lpa[0];
    }
    __syncthreads();
    if (z == 0) {
        float lp = lpa[0] + lpx[nl];
        float linv = 1.0f / lp;
        size_t abase = ((size_t)(b * NN) + n0 + nl) * 512 + h * 64 + quad * 4;
        #pragma unroll
        for (int dt = 0; dt < 4; dt++) {
            f32x4 other = *(f32x4*)(ox + ((wq * 4 + dt) * 64 + lane) * 4);
            __bf16 ov[4];
            #pragma unroll
            for (int r = 0; r < 4; r++)
                ov[r] = (__bf16)((o_p[dt][r] + other[r]) * linv);
            *(uint2*)(aout + abase + dt * 16) = *(uint2*)ov;
        }
    }
}

extern "C" void kernel_launch(void* const* d_in, const int* in_sizes, int n_in,
                              void* d_out, int out_size, void* d_ws, size_t ws_size,
                              hipStream_t stream)
{
    const float* h_   = (const float*)d_in[0];
    const float* obs  = (const float*)d_in[1];
    const float* Wq   = (const float*)d_in[2];
    const float* bq   = (const float*)d_in[3];
    const float* Wk   = (const float*)d_in[4];
    const float* bk   = (const float*)d_in[5];
    const float* Wv   = (const float*)d_in[6];
    const float* bv   = (const float*)d_in[7];
    const float* Wo   = (const float*)d_in[8];
    const float* bo   = (const float*)d_in[9];
    const float* Woq  = (const float*)d_in[10];
    const float* boq  = (const float*)d_in[11];
    const float* Wok  = (const float*)d_in[12];
    const float* bok  = (const float*)d_in[13];
    const float* varb = (const float*)d_in[14];
    const float* rtb  = (const float*)d_in[15];
    float* out = (float*)d_out;

    char* ws = (char*)d_ws;
    __bf16* h_bf    = (__bf16*)ws;                 ws += (size_t)NBN * 512 * 2;
    __bf16* qarr    = (__bf16*)ws;                 ws += (size_t)NBN * 512 * 2;
    __bf16* vt      = (__bf16*)ws;                 ws += (size_t)NBN * 512 * 2;
    __bf16* kx      = (__bf16*)ws;                 ws += ((size_t)32 * NN * 96 + 64) * 2;
    __bf16* attnout = (__bf16*)ws;                 ws += (size_t)NBN * 512 * 2;
    __bf16* WcatT   = (__bf16*)ws;                 ws += (size_t)1536 * 512 * 2;
    __bf16* WoT     = (__bf16*)ws;                 ws += (size_t)512 * 512 * 2;
    float*  biascat = (float*)ws;                  ws += 1536 * 4;

    prep<<<dim3(2176), dim3(256), 0, stream>>>(
        h_, obs, Wq, Wk, Wv, Wo, bq, bk, bv, Wok, bok,
        h_bf, WcatT, WoT, biascat, kx);
    gemm_mfma<128, true><<<dim3(12, 48), dim3(256), 0, stream>>>(
        h_bf, WcatT, biascat, nullptr, qarr, kx, vt);
    attn_mfma<<<dim3(32, 24), dim3(512), 0, stream>>>(qarr, kx, vt, obs, Woq, boq,
                                                      varb, rtb, attnout);
    gemm_mfma<64, false><<<dim3(4, 96), dim3(256), 0, stream>>>(
        attnout, WoT, bo, out, nullptr, nullptr, nullptr);
}

// Round 11
// 183.811 us; speedup vs baseline: 1.6687x; 1.6687x over previous
//
#include <hip/hip_runtime.h>
#include <math.h>

typedef __bf16 bf16x8 __attribute__((ext_vector_type(8)));
typedef float f32x4 __attribute__((ext_vector_type(4)));
typedef short short4v __attribute__((ext_vector_type(4)));
typedef short short8v __attribute__((ext_vector_type(8)));

#define NB 4
#define NT 48
#define NV 32
#define ND 512
#define NH 8
#define NN 1536   // T*V
#define NBN 6144  // B*N
#define L2E 1.44269504f

#define GLOAD_LDS(g, l) \
    __builtin_amdgcn_global_load_lds( \
        (const __attribute__((address_space(1))) void*)(g), \
        (__attribute__((address_space(3))) void*)(l), 16, 0, 0)

// ---------------------------------------------------------------------------
// prep: fused conv_h (blocks 0..1535) + weight transpose (1536..1791) +
// kx obs/zero segments (1792..2175).  log2e folded into Wq/bq scale.
// ---------------------------------------------------------------------------
__global__ __launch_bounds__(256) void prep(
    const float* __restrict__ h, const float* __restrict__ obs,
    const float* __restrict__ Wq, const float* __restrict__ Wk,
    const float* __restrict__ Wv, const float* __restrict__ Wo,
    const float* __restrict__ bq, const float* __restrict__ bk,
    const float* __restrict__ bv,
    const float* __restrict__ Wok, const float* __restrict__ bok,
    __bf16* __restrict__ h_bf, __bf16* __restrict__ WcatT,
    __bf16* __restrict__ WoT, float* __restrict__ biascat,
    __bf16* __restrict__ kx)
{
    __shared__ float ts[64][68];
    const int tid = threadIdx.x;
    const int bx = blockIdx.x;
    if (bx < 1536) {
        int t = bx * 256 + tid;
        const float4* src = (const float4*)h + (size_t)t * 2;
        float4 a = src[0], b = src[1];
        __bf16 r[8] = {(__bf16)a.x, (__bf16)a.y, (__bf16)a.z, (__bf16)a.w,
                       (__bf16)b.x, (__bf16)b.y, (__bf16)b.z, (__bf16)b.w};
        *(uint4*)(h_bf + (size_t)t * 8) = *(uint4*)r;
    } else if (bx < 1792) {
        int bw = bx - 1536;
        const int p = bw >> 6, tile = bw & 63;
        const int k0 = (tile >> 3) * 64, c0 = (tile & 7) * 64;
        const float* W = (p == 0) ? Wq : (p == 1) ? Wk : (p == 2) ? Wv : Wo;
        const float scale = (p == 0) ? 0.125f * L2E : 1.0f;
        #pragma unroll
        for (int i = 0; i < 4; i++) {
            int r = (tid >> 4) + i * 16;
            float4 v = *(const float4*)(W + (size_t)(k0 + r) * 512 + c0 + (tid & 15) * 4);
            *(float4*)&ts[r][(tid & 15) * 4] = v;
        }
        __syncthreads();
        __bf16 tmp[16];
        #pragma unroll
        for (int j = 0; j < 16; j++)
            tmp[j] = (__bf16)(ts[(tid & 3) * 16 + j][tid >> 2] * scale);
        int crow = c0 + (tid >> 2);
        __bf16* dst = (p < 3)
            ? WcatT + ((size_t)(p * 512 + crow)) * 512 + k0 + (tid & 3) * 16
            : WoT   + ((size_t)crow) * 512 + k0 + (tid & 3) * 16;
        *(uint4*)dst = *(uint4*)tmp;
        *(uint4*)(dst + 8) = *(uint4*)(tmp + 8);
        if (p < 3 && k0 == 0 && tid < 64) {
            const float* bb = (p == 0) ? bq : (p == 1) ? bk : bv;
            biascat[p * 512 + c0 + tid] = bb[c0 + tid] * scale;
        }
    } else {
        int t = (bx - 1792) * 256 + tid;               // 0..98303
        int row = t >> 1, half = t & 1;                // row = bh*1536 + n
        __bf16* dst = kx + (size_t)row * 96 + 64 + half * 16;
        if (half == 0) {
            int bh = row / NN, n = row - bh * NN;
            int b = bh >> 3, hh = bh & 7;
            size_t bn = (size_t)b * NN + n;
            float o0 = obs[bn * 2], o1 = obs[bn * 2 + 1];
            int f = hh * 16;
            __bf16 tmp[16];
            #pragma unroll
            for (int j = 0; j < 16; j++)
                tmp[j] = (__bf16)(o0 * Wok[f + j] + o1 * Wok[128 + f + j] + bok[f + j]);
            *(uint4*)dst       = *(uint4*)tmp;
            *(uint4*)(dst + 8) = *(uint4*)(tmp + 8);
        } else {
            uint4 z = {0, 0, 0, 0};
            *(uint4*)dst       = z;
            *(uint4*)(dst + 8) = z;
        }
    }
}

// ---------------------------------------------------------------------------
// bf16 MFMA GEMM — software-pipelined (R1, kept).  K-tile epilogue -> R3
// row-major kx.  V-tile epilogue -> vt4 packed-pair fragment layout
// (R6-verified).  Unchanged.
// ---------------------------------------------------------------------------
template<int TM, bool BF16OUT>
__global__ __launch_bounds__(256) void gemm_mfma(
    const __bf16* __restrict__ A, const __bf16* __restrict__ Bt,
    const float* __restrict__ bias, float* __restrict__ Cf,
    __bf16* __restrict__ qarr, __bf16* __restrict__ kx,
    __bf16* __restrict__ vt)
{
    constexpr int MT = TM / 32;
    __shared__ __align__(16) char smem[34816];
    char* const As0 = smem;
    char* const As1 = smem + TM * 64;
    char* const Bs0 = smem + TM * 128;
    char* const Bs1 = smem + TM * 128 + 8192;
    const int tid = threadIdx.x;
    const int w = tid >> 6, lane = tid & 63;
    const int quad = lane >> 4, l16 = lane & 15;
    const int wm = w >> 1, wn = w & 1;
    const int n0 = blockIdx.x * 128, m0 = blockIdx.y * TM;

    const int sm = tid >> 2;
    const int sk = ((tid & 3) ^ ((sm >> 1) & 3)) * 8;
    const __bf16* aptr = A  + (size_t)(m0 + sm) * 512 + sk;
    const __bf16* bptr = Bt + (size_t)(n0 + sm) * 512 + sk;

    f32x4 zero4 = {0.f, 0.f, 0.f, 0.f};
    f32x4 acc[MT][4];
    #pragma unroll
    for (int i = 0; i < MT; i++)
        #pragma unroll
        for (int j = 0; j < 4; j++) acc[i][j] = zero4;

    auto STAGE = [&](char* dA, char* dB, int kt) {
        GLOAD_LDS(aptr + kt, dA + tid * 16);
        if (TM == 128) GLOAD_LDS(aptr + 64 * 512 + kt, dA + 4096 + tid * 16);
        GLOAD_LDS(bptr + kt, dB + tid * 16);
        GLOAD_LDS(bptr + 64 * 512 + kt, dB + 4096 + tid * 16);
    };
    auto COMPUTE = [&](const char* Asb, const char* Bsb) {
        bf16x8 af[MT], bfr[4];
        #pragma unroll
        for (int mt = 0; mt < MT; mt++) {
            int rr = wm * (TM / 2) + mt * 16 + l16;
            af[mt] = *(const bf16x8*)(Asb + rr * 64 + (quad ^ ((rr >> 1) & 3)) * 16);
        }
        #pragma unroll
        for (int nt = 0; nt < 4; nt++) {
            int rr = wn * 64 + nt * 16 + l16;
            bfr[nt] = *(const bf16x8*)(Bsb + rr * 64 + (quad ^ ((rr >> 1) & 3)) * 16);
        }
        #pragma unroll
        for (int mt = 0; mt < MT; mt++)
            #pragma unroll
            for (int nt = 0; nt < 4; nt++)
                acc[mt][nt] = __builtin_amdgcn_mfma_f32_16x16x32_bf16(
                    af[mt], bfr[nt], acc[mt][nt], 0, 0, 0);
    };

    STAGE(As0, Bs0, 0);
    asm volatile("s_waitcnt vmcnt(0)" ::: "memory");
    __builtin_amdgcn_s_barrier();
    for (int kt = 0; kt < 512; kt += 64) {
        STAGE(As1, Bs1, kt + 32);          // always valid: last is kt=448 -> 480
        COMPUTE(As0, Bs0);
        asm volatile("s_waitcnt vmcnt(0)" ::: "memory");
        __builtin_amdgcn_s_barrier();
        if (kt + 64 < 512) STAGE(As0, Bs0, kt + 64);
        COMPUTE(As1, Bs1);
        asm volatile("s_waitcnt vmcnt(0)" ::: "memory");
        __builtin_amdgcn_s_barrier();
    }

    __syncthreads();   // frag reads done; smem becomes C-stage
    if (BF16OUT) {
        if (n0 >= 1024) {
            // ---- V tile: stage TRANSPOSED (CsT[col][136 rows]), write vt4 ----
            __bf16* CsT = (__bf16*)smem;
            #pragma unroll
            for (int nt = 0; nt < 4; nt++) {
                int cl = wn * 64 + nt * 16 + l16;
                float bia = bias[n0 + cl];
                #pragma unroll
                for (int mt = 0; mt < MT; mt++) {
                    int rl0 = wm * (TM / 2) + mt * 16 + quad * 4;
                    __bf16 pk[4];
                    #pragma unroll
                    for (int r = 0; r < 4; r++)
                        pk[r] = (__bf16)(acc[mt][nt][r] + bia);
                    *(uint2*)&CsT[cl * 136 + rl0] = *(uint2*)pk;
                }
            }
            __syncthreads();
            int cl = tid >> 1, half = tid & 1;
            int f0 = (n0 + cl) & 511;
            int hh = f0 >> 6, d = f0 & 63;
            int dt = d >> 4, l16v = d & 15;
            int bidx = m0 / NN, nm = m0 - bidx * NN;
            int bh = bidx * 8 + hh;
            int mtv = (nm >> 6) + half;
            #pragma unroll
            for (int j = 0; j < 8; j++) {
                uint4 v = *(uint4*)&CsT[cl * 136 + half * 64 + j * 8];
                __bf16* pp = (__bf16*)&v;
                int q0 = (j & 1) * 2;
                size_t fo = ((size_t)(bh * 24 + mtv) * 8 + (j >> 1) * 2 + (dt >> 1)) * 512
                            + (dt & 1) * 4 + l16v * 8;
                *(uint2*)(vt + fo + q0 * 128)       = *(uint2*)&pp[0];
                *(uint2*)(vt + fo + (q0 + 1) * 128) = *(uint2*)&pp[4];
            }
        } else {
            // ---- Q/K tile: row-major stage, routed stores (R3 form) ----
            __bf16* Cs = (__bf16*)smem;               // [TM][132]
            #pragma unroll
            for (int mt = 0; mt < MT; mt++)
                #pragma unroll
                for (int nt = 0; nt < 4; nt++) {
                    int cl = wn * 64 + nt * 16 + l16;
                    float bia = bias[n0 + cl];
                    #pragma unroll
                    for (int r = 0; r < 4; r++) {
                        int rl = wm * (TM / 2) + mt * 16 + quad * 4 + r;
                        Cs[rl * 132 + cl] = (__bf16)(acc[mt][nt][r] + bia);
                    }
                }
            __syncthreads();
            int rl = tid >> 1, hb = tid & 1;
            int grow = m0 + rl;
            int col0 = n0 + hb * 64;
            int p = col0 >> 9, f0 = col0 & 511, hh = f0 >> 6;
            int bidx = grow / NN, n = grow - bidx * NN;
            __bf16* dst = (p == 0) ? qarr + (size_t)grow * 512 + f0
                                   : kx + ((size_t)(bidx * 8 + hh) * NN + n) * 96;
            #pragma unroll
            for (int j = 0; j < 8; j++) {
                uint2 lo = *(uint2*)&Cs[rl * 132 + hb * 64 + j * 8];
                uint2 hi = *(uint2*)&Cs[rl * 132 + hb * 64 + j * 8 + 4];
                uint4 v = {lo.x, lo.y, hi.x, hi.y};
                *(uint4*)(dst + j * 8) = v;
            }
        }
    } else {
        float* Csf = (float*)smem;                // [64][132]
        #pragma unroll
        for (int mt = 0; mt < MT; mt++)
            #pragma unroll
            for (int nt = 0; nt < 4; nt++) {
                int cl = wn * 64 + nt * 16 + l16;
                float bia = bias[n0 + cl];
                #pragma unroll
                for (int r = 0; r < 4; r++) {
                    int rl = wm * (TM / 2) + mt * 16 + quad * 4 + r;
                    Csf[rl * 132 + cl] = acc[mt][nt][r] + bia;
                }
            }
        __syncthreads();
        int rl = tid >> 2, q4 = tid & 3;
        float* dst = Cf + (size_t)(m0 + rl) * 512 + n0 + q4 * 32;
        #pragma unroll
        for (int j = 0; j < 8; j++) {
            uint4 v = *(uint4*)&Csf[rl * 132 + q4 * 32 + j * 4];
            *(uint4*)(dst + j * 4) = v;
        }
    }
}

// ---------------------------------------------------------------------------
// Flash attention, n-split, INTRA-BLOCK KV-SPLIT (R11 = R10 with spill-free
// launch bounds).  grid (32,24), 512 threads: waves 0-3 process K-tiles
// 0..11, waves 4-7 tiles 12..23; per-half 16 KB Ks; combine in LDS at end.
// R7-R10 POST-MORTEM: __launch_bounds__(...,6) forced VGPR 84->40 via
// scratch spill (~600 MB phantom FETCH/WRITE, 50% HBM-bound).  (512,3)
// caps at 170 VGPR -> natural ~84-110 alloc, no spill; VGPR-limited
// residency 6 waves/EU = 3 blocks/CU = 24 waves/CU (2x R6's TLP, half
// the per-wave chain), with R6's clean 11 MB traffic.
// ---------------------------------------------------------------------------
__global__ __launch_bounds__(512, 3) void attn_mfma(
    const __bf16* __restrict__ qarr, const __bf16* __restrict__ kx,
    const __bf16* __restrict__ vt, const float* __restrict__ obs,
    const float* __restrict__ Woq, const float* __restrict__ boq,
    const float* __restrict__ varb, const float* __restrict__ rtb,
    __bf16* __restrict__ aout)
{
    __shared__ __align__(16) __bf16 Ks[2][64][128];  // per-half K tile, XOR-swz
    __shared__ float rts[96];
    __shared__ float lpx[64];

    const int tid = threadIdx.x;
    const int w = tid >> 6;            // 0..7
    const int z = w >> 2;              // half: 0 or 1
    const int wq = w & 3;              // wave-within-half
    const int lane = tid & 63;
    const int quad = lane >> 4, l16 = lane & 15;
    const int bh = blockIdx.x, qt = blockIdx.y;   // XCD-locality swizzle
    const int b = bh >> 3, h = bh & 7;
    const int n0 = qt * 64;
    const int mt0 = z * 12, mt1 = mt0 + 12;

    if (tid < 95) rts[tid] = rtb[h * 95 + tid] * L2E;

    // K staging (R3-proven map); each half stages into its own Ks[z] with
    // its 256 threads (tid4 = tid & 255 plays the old 256-thread tid role).
    const int tid4 = tid & 255;
    const int ck = (tid4 & 15) ^ ((tid4 >> 4) & 7);
    const __bf16* kbase = kx + (size_t)bh * NN * 96 + ck * 8;
    auto STAGE_K = [&](int m0s) {
        int rowg = tid4 >> 4;          // 0..15
        #pragma unroll
        for (int i = 0; i < 4; i++) {
            int row = i * 16 + rowg;
            GLOAD_LDS(kbase + (size_t)(m0s + row) * 96,
                      (char*)Ks + z * 16384 + i * 4096 + tid4 * 16);
        }
    };
    STAGE_K(mt0 * 64);

    // V fragment base (vt4)
    const __bf16* vwb = vt + (size_t)bh * 24 * 4096 + lane * 8;

    // Q fragments (B-operand): lane l16 holds row n = wq*16+l16 (both halves
    // load the same rows — duplicated read, L2-hit)
    const int nl = wq * 16 + l16;
    const size_t qrow = (size_t)(b * NN + n0 + nl);
    bf16x8 bq_[3];
    bq_[0] = *(const bf16x8*)(qarr + qrow * 512 + h * 64 + quad * 8);
    bq_[1] = *(const bf16x8*)(qarr + qrow * 512 + h * 64 + 32 + quad * 8);
    {   // inline oq: logical k 64..95 -> oq[0..15] then zeros; 0.25*log2e folded
        uint4 a2u = {0u, 0u, 0u, 0u};
        if (quad < 2) {
            float o0 = obs[qrow * 2], o1 = obs[qrow * 2 + 1];
            int f = h * 16 + quad * 8;
            const float sc = 0.25f * L2E;
            __bf16 tmp[8];
            #pragma unroll
            for (int j = 0; j < 8; j++)
                tmp[j] = (__bf16)(sc * (o0 * Woq[f + j] + o1 * Woq[128 + f + j]
                                        + boq[f + j]));
            a2u = *(uint4*)tmp;
        }
        bq_[2] = *(bf16x8*)&a2u;
    }

    // var-bias: row (n&31) fixed per lane; m&31 = (ct&1)*16 + quad*4 + r
    const int rm = (wq & 1) * 16 + l16;
    float4 vbA = *(const float4*)(varb + h * 1024 + rm * 32 + quad * 4);
    float4 vbB = *(const float4*)(varb + h * 1024 + rm * 32 + 16 + quad * 4);
    float vA[4] = {vbA.x * L2E, vbA.y * L2E, vbA.z * L2E, vbA.w * L2E};
    float vB[4] = {vbB.x * L2E, vbB.y * L2E, vbB.z * L2E, vbB.w * L2E};
    const int tn = 2 * qt + (wq >> 1);

    // ones fragment for the lp MFMA
    union { __bf16 e[4]; short4v s; } one_u;
    #pragma unroll
    for (int j = 0; j < 4; j++) one_u.e[j] = (__bf16)1.0f;
    const short4v ones = one_u.s;

    f32x4 zero4 = {0.f, 0.f, 0.f, 0.f};
    f32x4 o_p[4];                     // [dt]: row d = dt*16+quad*4+r, col n=l16
    f32x4 lpa = zero4;
    #pragma unroll
    for (int i = 0; i < 4; i++) o_p[i] = zero4;

    asm volatile("s_waitcnt vmcnt(0) lgkmcnt(0)" ::: "memory");
    __builtin_amdgcn_s_barrier();     // tiles mt0 (both halves) staged + rts

    for (int mt = mt0; mt < mt1; mt++) {
        // V fragments (global->VGPR, consumed at PV; covered by QK)
        short8v v0[8];
        {
            const __bf16* vp = vwb + (size_t)mt * 4096;
            #pragma unroll
            for (int fi = 0; fi < 8; fi++)
                v0[fi] = *(const short8v*)(vp + fi * 512);
        }
        // ---- S^T = K.Q^T over K=96 (reads own half's Ks) ----
        f32x4 sc[4];
        __builtin_amdgcn_s_setprio(1);
        #pragma unroll
        for (int ct = 0; ct < 4; ct++) {
            f32x4 d = zero4;
            int row = ct * 16 + l16;
            #pragma unroll
            for (int ks = 0; ks < 3; ks++) {
                bf16x8 kf = *(const bf16x8*)((const char*)Ks + z * 16384
                                + row * 256 + (((ks * 4 + quad) ^ (row & 7)) * 16));
                d = __builtin_amdgcn_mfma_f32_16x16x32_bf16(kf, bq_[ks], d, 0, 0, 0);
            }
            sc[ct] = d;
        }
        __builtin_amdgcn_s_setprio(0);

        // all waves done reading their Ks -> safe to overwrite
        asm volatile("s_waitcnt lgkmcnt(0)" ::: "memory");
        __builtin_amdgcn_s_barrier();
        if (mt + 1 < mt1) STAGE_K((mt + 1) * 64);

        // ---- biases + exp2 -> P in registers ----
        float tb0 = rts[tn - 2 * mt + 47];
        float tb1 = rts[tn - 2 * mt + 46];
        short4v pf[4];
        #pragma unroll
        for (int ct = 0; ct < 4; ct++) {
            float tb = (ct & 2) ? tb1 : tb0;
            const float* vv = (ct & 1) ? vB : vA;
            union { __bf16 e[4]; short4v s; } pk;
            #pragma unroll
            for (int r = 0; r < 4; r++)
                pk.e[r] = (__bf16)exp2f(sc[ct][r] + tb + vv[r]);
            pf[ct] = pk.s;
        }

        // ---- O^T += V^T.P^T (16x16x16, register A/B) + lp ----
        __builtin_amdgcn_s_setprio(1);
        #pragma unroll
        for (int ct = 0; ct < 4; ct++) {
            lpa = __builtin_amdgcn_mfma_f32_16x16x16bf16_1k(ones, pf[ct], lpa, 0, 0, 0);
            #pragma unroll
            for (int dt = 0; dt < 4; dt++) {
                short8v v8 = v0[ct * 2 + (dt >> 1)];
                short4v va = (dt & 1)
                    ? __builtin_shufflevector(v8, v8, 4, 5, 6, 7)
                    : __builtin_shufflevector(v8, v8, 0, 1, 2, 3);
                o_p[dt] = __builtin_amdgcn_mfma_f32_16x16x16bf16_1k(
                    va, pf[ct], o_p[dt], 0, 0, 0);
            }
        }
        __builtin_amdgcn_s_setprio(0);

        // staged K landed everywhere
        asm volatile("s_waitcnt vmcnt(0)" ::: "memory");
        __builtin_amdgcn_s_barrier();
    }

    // ---- combine halves in LDS (reuse Ks), then normalize + store bf16 ----
    float* ox = (float*)Ks;           // 16 KB: [wq][dt][lane] f32x4
    if (z == 1) {
        #pragma unroll
        for (int dt = 0; dt < 4; dt++)
            *(f32x4*)(ox + ((wq * 4 + dt) * 64 + lane) * 4) = o_p[dt];
        if (quad == 0) lpx[nl] = lpa[0];
    }
    __syncthreads();
    if (z == 0) {
        float lp = lpa[0] + lpx[nl];
        float linv = 1.0f / lp;
        size_t abase = ((size_t)(b * NN) + n0 + nl) * 512 + h * 64 + quad * 4;
        #pragma unroll
        for (int dt = 0; dt < 4; dt++) {
            f32x4 other = *(f32x4*)(ox + ((wq * 4 + dt) * 64 + lane) * 4);
            __bf16 ov[4];
            #pragma unroll
            for (int r = 0; r < 4; r++)
                ov[r] = (__bf16)((o_p[dt][r] + other[r]) * linv);
            *(uint2*)(aout + abase + dt * 16) = *(uint2*)ov;
        }
    }
}

extern "C" void kernel_launch(void* const* d_in, const int* in_sizes, int n_in,
                              void* d_out, int out_size, void* d_ws, size_t ws_size,
                              hipStream_t stream)
{
    const float* h_   = (const float*)d_in[0];
    const float* obs  = (const float*)d_in[1];
    const float* Wq   = (const float*)d_in[2];
    const float* bq   = (const float*)d_in[3];
    const float* Wk   = (const float*)d_in[4];
    const float* bk   = (const float*)d_in[5];
    const float* Wv   = (const float*)d_in[6];
    const float* bv   = (const float*)d_in[7];
    const float* Wo   = (const float*)d_in[8];
    const float* bo   = (const float*)d_in[9];
    const float* Woq  = (const float*)d_in[10];
    const float* boq  = (const float*)d_in[11];
    const float* Wok  = (const float*)d_in[12];
    const float* bok  = (const float*)d_in[13];
    const float* varb = (const float*)d_in[14];
    const float* rtb  = (const float*)d_in[15];
    float* out = (float*)d_out;

    char* ws = (char*)d_ws;
    __bf16* h_bf    = (__bf16*)ws;                 ws += (size_t)NBN * 512 * 2;
    __bf16* qarr    = (__bf16*)ws;                 ws += (size_t)NBN * 512 * 2;
    __bf16* vt      = (__bf16*)ws;                 ws += (size_t)NBN * 512 * 2;
    __bf16* kx      = (__bf16*)ws;                 ws += ((size_t)32 * NN * 96 + 64) * 2;
    __bf16* attnout = (__bf16*)ws;                 ws += (size_t)NBN * 512 * 2;
    __bf16* WcatT   = (__bf16*)ws;                 ws += (size_t)1536 * 512 * 2;
    __bf16* WoT     = (__bf16*)ws;                 ws += (size_t)512 * 512 * 2;
    float*  biascat = (float*)ws;                  ws += 1536 * 4;

    prep<<<dim3(2176), dim3(256), 0, stream>>>(
        h_, obs, Wq, Wk, Wv, Wo, bq, bk, bv, Wok, bok,
        h_bf, WcatT, WoT, biascat, kx);
    gemm_mfma<128, true><<<dim3(12, 48), dim3(256), 0, stream>>>(
        h_bf, WcatT, biascat, nullptr, qarr, kx, vt);
    attn_mfma<<<dim3(32, 24), dim3(512), 0, stream>>>(qarr, kx, vt, obs, Woq, boq,
                                                      varb, rtb, attnout);
    gemm_mfma<64, false><<<dim3(4, 96), dim3(256), 0, stream>>>(
        attnout, WoT, bo, out, nullptr, nullptr, nullptr);
}

// Round 12
// 178.764 us; speedup vs baseline: 1.7158x; 1.0282x over previous
//
#include <hip/hip_runtime.h>
#include <math.h>

typedef __bf16 bf16x8 __attribute__((ext_vector_type(8)));
typedef float f32x4 __attribute__((ext_vector_type(4)));
typedef short short4v __attribute__((ext_vector_type(4)));
typedef short short8v __attribute__((ext_vector_type(8)));

#define NB 4
#define NT 48
#define NV 32
#define ND 512
#define NH 8
#define NN 1536   // T*V
#define NBN 6144  // B*N
#define L2E 1.44269504f

#define GLOAD_LDS(g, l) \
    __builtin_amdgcn_global_load_lds( \
        (const __attribute__((address_space(1))) void*)(g), \
        (__attribute__((address_space(3))) void*)(l), 16, 0, 0)

// ---------------------------------------------------------------------------
// prep: fused conv_h (blocks 0..1535) + weight transpose (1536..1791) +
// kx obs/zero segments (1792..2175).  log2e folded into Wq/bq scale.
// kx layout = R3 row-major: kx[(bh*NN + n)*96 + k], k 0..63 content (gemm),
// 64..79 oq, 80..95 zeros (prep).
// ---------------------------------------------------------------------------
__global__ __launch_bounds__(256) void prep(
    const float* __restrict__ h, const float* __restrict__ obs,
    const float* __restrict__ Wq, const float* __restrict__ Wk,
    const float* __restrict__ Wv, const float* __restrict__ Wo,
    const float* __restrict__ bq, const float* __restrict__ bk,
    const float* __restrict__ bv,
    const float* __restrict__ Wok, const float* __restrict__ bok,
    __bf16* __restrict__ h_bf, __bf16* __restrict__ WcatT,
    __bf16* __restrict__ WoT, float* __restrict__ biascat,
    __bf16* __restrict__ kx)
{
    __shared__ float ts[64][68];
    const int tid = threadIdx.x;
    const int bx = blockIdx.x;
    if (bx < 1536) {
        int t = bx * 256 + tid;
        const float4* src = (const float4*)h + (size_t)t * 2;
        float4 a = src[0], b = src[1];
        __bf16 r[8] = {(__bf16)a.x, (__bf16)a.y, (__bf16)a.z, (__bf16)a.w,
                       (__bf16)b.x, (__bf16)b.y, (__bf16)b.z, (__bf16)b.w};
        *(uint4*)(h_bf + (size_t)t * 8) = *(uint4*)r;
    } else if (bx < 1792) {
        int bw = bx - 1536;
        const int p = bw >> 6, tile = bw & 63;
        const int k0 = (tile >> 3) * 64, c0 = (tile & 7) * 64;
        const float* W = (p == 0) ? Wq : (p == 1) ? Wk : (p == 2) ? Wv : Wo;
        const float scale = (p == 0) ? 0.125f * L2E : 1.0f;
        #pragma unroll
        for (int i = 0; i < 4; i++) {
            int r = (tid >> 4) + i * 16;
            float4 v = *(const float4*)(W + (size_t)(k0 + r) * 512 + c0 + (tid & 15) * 4);
            *(float4*)&ts[r][(tid & 15) * 4] = v;
        }
        __syncthreads();
        __bf16 tmp[16];
        #pragma unroll
        for (int j = 0; j < 16; j++)
            tmp[j] = (__bf16)(ts[(tid & 3) * 16 + j][tid >> 2] * scale);
        int crow = c0 + (tid >> 2);
        __bf16* dst = (p < 3)
            ? WcatT + ((size_t)(p * 512 + crow)) * 512 + k0 + (tid & 3) * 16
            : WoT   + ((size_t)crow) * 512 + k0 + (tid & 3) * 16;
        *(uint4*)dst = *(uint4*)tmp;
        *(uint4*)(dst + 8) = *(uint4*)(tmp + 8);
        if (p < 3 && k0 == 0 && tid < 64) {
            const float* bb = (p == 0) ? bq : (p == 1) ? bk : bv;
            biascat[p * 512 + c0 + tid] = bb[c0 + tid] * scale;
        }
    } else {
        int t = (bx - 1792) * 256 + tid;               // 0..98303
        int row = t >> 1, half = t & 1;                // row = bh*1536 + n
        __bf16* dst = kx + (size_t)row * 96 + 64 + half * 16;
        if (half == 0) {
            int bh = row / NN, n = row - bh * NN;
            int b = bh >> 3, hh = bh & 7;
            size_t bn = (size_t)b * NN + n;
            float o0 = obs[bn * 2], o1 = obs[bn * 2 + 1];
            int f = hh * 16;
            __bf16 tmp[16];
            #pragma unroll
            for (int j = 0; j < 16; j++)
                tmp[j] = (__bf16)(o0 * Wok[f + j] + o1 * Wok[128 + f + j] + bok[f + j]);
            *(uint4*)dst       = *(uint4*)tmp;
            *(uint4*)(dst + 8) = *(uint4*)(tmp + 8);
        } else {
            uint4 z = {0, 0, 0, 0};
            *(uint4*)dst       = z;
            *(uint4*)(dst + 8) = z;
        }
    }
}

// ---------------------------------------------------------------------------
// bf16 MFMA GEMM — software-pipelined (R1, kept).  K-tile epilogue -> R3
// row-major kx.  V-tile epilogue -> vt4 packed-pair fragment layout for
// 16x16x16 PV A-frags:
//   slot fi = wv*2 + (dt>>1), addr = ((bh*24+mt)*8 + fi)*512 + lane*8 +
//   (dt&1)*4 + jj;  lane=(quad,l16) holds d = dt*16+l16, m16 = quad*4+jj.
// ---------------------------------------------------------------------------
template<int TM, bool BF16OUT>
__global__ __launch_bounds__(256) void gemm_mfma(
    const __bf16* __restrict__ A, const __bf16* __restrict__ Bt,
    const float* __restrict__ bias, float* __restrict__ Cf,
    __bf16* __restrict__ qarr, __bf16* __restrict__ kx,
    __bf16* __restrict__ vt)
{
    constexpr int MT = TM / 32;
    __shared__ __align__(16) char smem[34816];
    char* const As0 = smem;
    char* const As1 = smem + TM * 64;
    char* const Bs0 = smem + TM * 128;
    char* const Bs1 = smem + TM * 128 + 8192;
    const int tid = threadIdx.x;
    const int w = tid >> 6, lane = tid & 63;
    const int quad = lane >> 4, l16 = lane & 15;
    const int wm = w >> 1, wn = w & 1;
    const int n0 = blockIdx.x * 128, m0 = blockIdx.y * TM;

    const int sm = tid >> 2;
    const int sk = ((tid & 3) ^ ((sm >> 1) & 3)) * 8;
    const __bf16* aptr = A  + (size_t)(m0 + sm) * 512 + sk;
    const __bf16* bptr = Bt + (size_t)(n0 + sm) * 512 + sk;

    f32x4 zero4 = {0.f, 0.f, 0.f, 0.f};
    f32x4 acc[MT][4];
    #pragma unroll
    for (int i = 0; i < MT; i++)
        #pragma unroll
        for (int j = 0; j < 4; j++) acc[i][j] = zero4;

    auto STAGE = [&](char* dA, char* dB, int kt) {
        GLOAD_LDS(aptr + kt, dA + tid * 16);
        if (TM == 128) GLOAD_LDS(aptr + 64 * 512 + kt, dA + 4096 + tid * 16);
        GLOAD_LDS(bptr + kt, dB + tid * 16);
        GLOAD_LDS(bptr + 64 * 512 + kt, dB + 4096 + tid * 16);
    };
    auto COMPUTE = [&](const char* Asb, const char* Bsb) {
        bf16x8 af[MT], bfr[4];
        #pragma unroll
        for (int mt = 0; mt < MT; mt++) {
            int rr = wm * (TM / 2) + mt * 16 + l16;
            af[mt] = *(const bf16x8*)(Asb + rr * 64 + (quad ^ ((rr >> 1) & 3)) * 16);
        }
        #pragma unroll
        for (int nt = 0; nt < 4; nt++) {
            int rr = wn * 64 + nt * 16 + l16;
            bfr[nt] = *(const bf16x8*)(Bsb + rr * 64 + (quad ^ ((rr >> 1) & 3)) * 16);
        }
        #pragma unroll
        for (int mt = 0; mt < MT; mt++)
            #pragma unroll
            for (int nt = 0; nt < 4; nt++)
                acc[mt][nt] = __builtin_amdgcn_mfma_f32_16x16x32_bf16(
                    af[mt], bfr[nt], acc[mt][nt], 0, 0, 0);
    };

    STAGE(As0, Bs0, 0);
    asm volatile("s_waitcnt vmcnt(0)" ::: "memory");
    __builtin_amdgcn_s_barrier();
    for (int kt = 0; kt < 512; kt += 64) {
        STAGE(As1, Bs1, kt + 32);          // always valid: last is kt=448 -> 480
        COMPUTE(As0, Bs0);
        asm volatile("s_waitcnt vmcnt(0)" ::: "memory");
        __builtin_amdgcn_s_barrier();
        if (kt + 64 < 512) STAGE(As0, Bs0, kt + 64);
        COMPUTE(As1, Bs1);
        asm volatile("s_waitcnt vmcnt(0)" ::: "memory");
        __builtin_amdgcn_s_barrier();
    }

    __syncthreads();   // frag reads done; smem becomes C-stage
    if (BF16OUT) {
        if (n0 >= 1024) {
            // ---- V tile: stage TRANSPOSED (CsT[col][136 rows]), write vt4 ----
            __bf16* CsT = (__bf16*)smem;
            #pragma unroll
            for (int nt = 0; nt < 4; nt++) {
                int cl = wn * 64 + nt * 16 + l16;
                float bia = bias[n0 + cl];
                #pragma unroll
                for (int mt = 0; mt < MT; mt++) {
                    int rl0 = wm * (TM / 2) + mt * 16 + quad * 4;
                    __bf16 pk[4];
                    #pragma unroll
                    for (int r = 0; r < 4; r++)
                        pk[r] = (__bf16)(acc[mt][nt][r] + bia);
                    *(uint2*)&CsT[cl * 136 + rl0] = *(uint2*)pk;
                }
            }
            __syncthreads();
            int cl = tid >> 1, half = tid & 1;
            int f0 = (n0 + cl) & 511;
            int hh = f0 >> 6, d = f0 & 63;
            int dt = d >> 4, l16v = d & 15;
            int bidx = m0 / NN, nm = m0 - bidx * NN;
            int bh = bidx * 8 + hh;
            int mtv = (nm >> 6) + half;
            #pragma unroll
            for (int j = 0; j < 8; j++) {
                uint4 v = *(uint4*)&CsT[cl * 136 + half * 64 + j * 8];
                __bf16* pp = (__bf16*)&v;
                int q0 = (j & 1) * 2;
                size_t fo = ((size_t)(bh * 24 + mtv) * 8 + (j >> 1) * 2 + (dt >> 1)) * 512
                            + (dt & 1) * 4 + l16v * 8;
                *(uint2*)(vt + fo + q0 * 128)       = *(uint2*)&pp[0];
                *(uint2*)(vt + fo + (q0 + 1) * 128) = *(uint2*)&pp[4];
            }
        } else {
            // ---- Q/K tile: row-major stage, routed stores (R3 form) ----
            __bf16* Cs = (__bf16*)smem;               // [TM][132]
            #pragma unroll
            for (int mt = 0; mt < MT; mt++)
                #pragma unroll
                for (int nt = 0; nt < 4; nt++) {
                    int cl = wn * 64 + nt * 16 + l16;
                    float bia = bias[n0 + cl];
                    #pragma unroll
                    for (int r = 0; r < 4; r++) {
                        int rl = wm * (TM / 2) + mt * 16 + quad * 4 + r;
                        Cs[rl * 132 + cl] = (__bf16)(acc[mt][nt][r] + bia);
                    }
                }
            __syncthreads();
            int rl = tid >> 1, hb = tid & 1;
            int grow = m0 + rl;
            int col0 = n0 + hb * 64;
            int p = col0 >> 9, f0 = col0 & 511, hh = f0 >> 6;
            int bidx = grow / NN, n = grow - bidx * NN;
            __bf16* dst = (p == 0) ? qarr + (size_t)grow * 512 + f0
                                   : kx + ((size_t)(bidx * 8 + hh) * NN + n) * 96;
            #pragma unroll
            for (int j = 0; j < 8; j++) {
                uint2 lo = *(uint2*)&Cs[rl * 132 + hb * 64 + j * 8];
                uint2 hi = *(uint2*)&Cs[rl * 132 + hb * 64 + j * 8 + 4];
                uint4 v = {lo.x, lo.y, hi.x, hi.y};
                *(uint4*)(dst + j * 8) = v;
            }
        }
    } else {
        float* Csf = (float*)smem;                // [64][132]
        #pragma unroll
        for (int mt = 0; mt < MT; mt++)
            #pragma unroll
            for (int nt = 0; nt < 4; nt++) {
                int cl = wn * 64 + nt * 16 + l16;
                float bia = bias[n0 + cl];
                #pragma unroll
                for (int r = 0; r < 4; r++) {
                    int rl = wm * (TM / 2) + mt * 16 + quad * 4 + r;
                    Csf[rl * 132 + cl] = acc[mt][nt][r] + bia;
                }
            }
        __syncthreads();
        int rl = tid >> 2, q4 = tid & 3;
        float* dst = Cf + (size_t)(m0 + rl) * 512 + n0 + q4 * 32;
        #pragma unroll
        for (int j = 0; j < 8; j++) {
            uint4 v = *(uint4*)&Csf[rl * 132 + q4 * 32 + j * 4];
            *(uint4*)(dst + j * 4) = v;
        }
    }
}

// ---------------------------------------------------------------------------
// Flash attention, n-split (R6 — best measured: 56.8 us attn, 176.6 total):
//  * P in REGISTERS: PV uses 16x16x16 MFMAs whose B-frag layout (k=quad*4+j,
//    col=l16) equals the QK C-layout (m=quad*4+r, n=l16) — no Ps LDS.
//  * V from registers via vt4 packed-pair frags (8 x 16B loads/tile).
//  * Double K-tile LDS (Ks[2], 32KB): QK of BOTH tiles before one barrier,
//    next-pair staging covered by softmax+PV of both tiles.  2 barriers /
//    2 tiles.  LDS 33.2 KB.
//  * lp via MFMA-with-ones: no adds, no end shuffles.
// R7-R11 post-mortem (locked): KV-split variants at 16-60% occupancy with
// clean traffic all land at 61-65 us — attn time is invariant to TLP,
// barrier count, chain length, and LDS size across 13 variants.  This
// configuration is the empirical optimum.
// ---------------------------------------------------------------------------
__global__ __launch_bounds__(256, 3) void attn_mfma(
    const __bf16* __restrict__ qarr, const __bf16* __restrict__ kx,
    const __bf16* __restrict__ vt, const float* __restrict__ obs,
    const float* __restrict__ Woq, const float* __restrict__ boq,
    const float* __restrict__ varb, const float* __restrict__ rtb,
    __bf16* __restrict__ aout)
{
    __shared__ __align__(16) __bf16 Ks[2][64][128];  // double K-tile, XOR-swz
    __shared__ float rts[96];

    const int tid = threadIdx.x;
    const int w = tid >> 6, lane = tid & 63;
    const int quad = lane >> 4, l16 = lane & 15;
    const int bh = blockIdx.x, qt = blockIdx.y;   // XCD-locality swizzle
    const int b = bh >> 3, h = bh & 7;
    const int n0 = qt * 64;

    if (tid < 95) rts[tid] = rtb[h * 95 + tid] * L2E;

    // K staging map (R3-proven)
    const int ck = (tid & 15) ^ ((tid >> 4) & 7);
    const __bf16* kbase = kx + (size_t)bh * NN * 96 + ck * 8;
    auto STAGE_K = [&](int p, int m0s) {
        #pragma unroll
        for (int i = 0; i < 4; i++) {
            int row = i * 16 + (tid >> 4);
            GLOAD_LDS(kbase + (size_t)(m0s + row) * 96,
                      (char*)Ks + p * 16384 + i * 4096 + tid * 16);
        }
    };
    STAGE_K(0, 0);
    STAGE_K(1, 64);

    // V fragment base (vt4): slot fi -> ((bh*24+mt)*8 + fi)*512 + lane*8
    const __bf16* vwb = vt + (size_t)bh * 24 * 4096 + lane * 8;

    // Q fragments (B-operand): lane l16 holds row n = w*16+l16  (R3 form)
    const int nl = w * 16 + l16;
    const size_t qrow = (size_t)(b * NN + n0 + nl);
    bf16x8 bq_[3];
    bq_[0] = *(const bf16x8*)(qarr + qrow * 512 + h * 64 + quad * 8);
    bq_[1] = *(const bf16x8*)(qarr + qrow * 512 + h * 64 + 32 + quad * 8);
    {   // inline oq: logical k 64..95 -> oq[0..15] then zeros; 0.25*log2e folded
        uint4 a2u = {0u, 0u, 0u, 0u};
        if (quad < 2) {
            float o0 = obs[qrow * 2], o1 = obs[qrow * 2 + 1];
            int f = h * 16 + quad * 8;
            const float sc = 0.25f * L2E;
            __bf16 tmp[8];
            #pragma unroll
            for (int j = 0; j < 8; j++)
                tmp[j] = (__bf16)(sc * (o0 * Woq[f + j] + o1 * Woq[128 + f + j]
                                        + boq[f + j]));
            a2u = *(uint4*)tmp;
        }
        bq_[2] = *(bf16x8*)&a2u;
    }

    // var-bias: row (n&31) fixed per lane; m&31 = (ct&1)*16 + quad*4 + r
    const int rm = (w & 1) * 16 + l16;
    float4 vbA = *(const float4*)(varb + h * 1024 + rm * 32 + quad * 4);
    float4 vbB = *(const float4*)(varb + h * 1024 + rm * 32 + 16 + quad * 4);
    float vA[4] = {vbA.x * L2E, vbA.y * L2E, vbA.z * L2E, vbA.w * L2E};
    float vB[4] = {vbB.x * L2E, vbB.y * L2E, vbB.z * L2E, vbB.w * L2E};
    const int tn = 2 * qt + (w >> 1);

    // ones fragment for the lp MFMA
    union { __bf16 e[4]; short4v s; } one_u;
    #pragma unroll
    for (int j = 0; j < 4; j++) one_u.e[j] = (__bf16)1.0f;
    const short4v ones = one_u.s;

    f32x4 zero4 = {0.f, 0.f, 0.f, 0.f};
    f32x4 o_p[4];                     // [dt]: row=d (quad*4+r within dt), col=n=l16
    f32x4 lpa = zero4;                // all rows equal = lp[n=l16]
    #pragma unroll
    for (int i = 0; i < 4; i++) o_p[i] = zero4;

    auto QK = [&](int p, f32x4* sc) {
        __builtin_amdgcn_s_setprio(1);
        #pragma unroll
        for (int ct = 0; ct < 4; ct++) {
            f32x4 d = zero4;
            int row = ct * 16 + l16;
            #pragma unroll
            for (int ks = 0; ks < 3; ks++) {
                bf16x8 kf = *(const bf16x8*)((const char*)Ks + p * 16384
                                + row * 256 + (((ks * 4 + quad) ^ (row & 7)) * 16));
                d = __builtin_amdgcn_mfma_f32_16x16x32_bf16(kf, bq_[ks], d, 0, 0, 0);
            }
            sc[ct] = d;
        }
        __builtin_amdgcn_s_setprio(0);
    };
    auto SM = [&](const f32x4* sc, int mt, short4v* pf) {
        float tb0 = rts[tn - 2 * mt + 47];
        float tb1 = rts[tn - 2 * mt + 46];
        #pragma unroll
        for (int ct = 0; ct < 4; ct++) {
            float tb = (ct & 2) ? tb1 : tb0;
            const float* vv = (ct & 1) ? vB : vA;
            union { __bf16 e[4]; short4v s; } pk;
            #pragma unroll
            for (int r = 0; r < 4; r++)
                pk.e[r] = (__bf16)exp2f(sc[ct][r] + tb + vv[r]);
            pf[ct] = pk.s;
        }
    };
    auto PV = [&](const short8v* vfr, const short4v* pf) {
        __builtin_amdgcn_s_setprio(1);
        #pragma unroll
        for (int ct = 0; ct < 4; ct++) {
            lpa = __builtin_amdgcn_mfma_f32_16x16x16bf16_1k(ones, pf[ct], lpa, 0, 0, 0);
            #pragma unroll
            for (int dt = 0; dt < 4; dt++) {
                short8v v8 = vfr[ct * 2 + (dt >> 1)];
                short4v va = (dt & 1)
                    ? __builtin_shufflevector(v8, v8, 4, 5, 6, 7)
                    : __builtin_shufflevector(v8, v8, 0, 1, 2, 3);
                o_p[dt] = __builtin_amdgcn_mfma_f32_16x16x16bf16_1k(
                    va, pf[ct], o_p[dt], 0, 0, 0);
            }
        }
        __builtin_amdgcn_s_setprio(0);
    };

    __syncthreads();   // tiles 0,1 staged + rts visible

    for (int i = 0; i < 12; i++) {
        const int mt0 = 2 * i;
        // V fragments for tile mt0 (global->VGPR, consumed at PV0)
        short8v v0[8];
        {
            const __bf16* vp = vwb + (size_t)mt0 * 4096;
            #pragma unroll
            for (int fi = 0; fi < 8; fi++)
                v0[fi] = *(const short8v*)(vp + fi * 512);
        }
        f32x4 sc0[4], sc1[4];
        QK(0, sc0);
        QK(1, sc1);
        __syncthreads();             // all waves done reading Ks pair
        if (i < 11) {
            STAGE_K(0, (mt0 + 2) * 64);
            STAGE_K(1, (mt0 + 3) * 64);
        }
        short4v p0[4];
        SM(sc0, mt0, p0);
        // V fragments for tile mt0+1 (covered by PV0 + SM1)
        short8v v1[8];
        {
            const __bf16* vp = vwb + (size_t)(mt0 + 1) * 4096;
            #pragma unroll
            for (int fi = 0; fi < 8; fi++)
                v1[fi] = *(const short8v*)(vp + fi * 512);
        }
        PV(v0, p0);
        short4v p1[4];
        SM(sc1, mt0 + 1, p1);
        PV(v1, p1);
        __syncthreads();             // staged K pair landed everywhere
    }

    // ---- epilogue: lp complete per lane (col n=l16), direct store ----
    float linv = 1.0f / lpa[0];
    size_t abase = ((size_t)(b * NN) + n0 + nl) * 512 + h * 64 + quad * 4;
    #pragma unroll
    for (int dt = 0; dt < 4; dt++) {
        __bf16 ov[4];
        #pragma unroll
        for (int r = 0; r < 4; r++) ov[r] = (__bf16)(o_p[dt][r] * linv);
        *(uint2*)(aout + abase + dt * 16) = *(uint2*)ov;
    }
}

extern "C" void kernel_launch(void* const* d_in, const int* in_sizes, int n_in,
                              void* d_out, int out_size, void* d_ws, size_t ws_size,
                              hipStream_t stream)
{
    const float* h_   = (const float*)d_in[0];
    const float* obs  = (const float*)d_in[1];
    const float* Wq   = (const float*)d_in[2];
    const float* bq   = (const float*)d_in[3];
    const float* Wk   = (const float*)d_in[4];
    const float* bk   = (const float*)d_in[5];
    const float* Wv   = (const float*)d_in[6];
    const float* bv   = (const float*)d_in[7];
    const float* Wo   = (const float*)d_in[8];
    const float* bo   = (const float*)d_in[9];
    const float* Woq  = (const float*)d_in[10];
    const float* boq  = (const float*)d_in[11];
    const float* Wok  = (const float*)d_in[12];
    const float* bok  = (const float*)d_in[13];
    const float* varb = (const float*)d_in[14];
    const float* rtb  = (const float*)d_in[15];
    float* out = (float*)d_out;

    char* ws = (char*)d_ws;
    __bf16* h_bf    = (__bf16*)ws;                 ws += (size_t)NBN * 512 * 2;
    __bf16* qarr    = (__bf16*)ws;                 ws += (size_t)NBN * 512 * 2;
    __bf16* vt      = (__bf16*)ws;                 ws += (size_t)NBN * 512 * 2;
    __bf16* kx      = (__bf16*)ws;                 ws += ((size_t)32 * NN * 96 + 64) * 2;
    __bf16* attnout = (__bf16*)ws;                 ws += (size_t)NBN * 512 * 2;
    __bf16* WcatT   = (__bf16*)ws;                 ws += (size_t)1536 * 512 * 2;
    __bf16* WoT     = (__bf16*)ws;                 ws += (size_t)512 * 512 * 2;
    float*  biascat = (float*)ws;                  ws += 1536 * 4;

    prep<<<dim3(2176), dim3(256), 0, stream>>>(
        h_, obs, Wq, Wk, Wv, Wo, bq, bk, bv, Wok, bok,
        h_bf, WcatT, WoT, biascat, kx);
    gemm_mfma<128, true><<<dim3(12, 48), dim3(256), 0, stream>>>(
        h_bf, WcatT, biascat, nullptr, qarr, kx, vt);
    attn_mfma<<<dim3(32, 24), dim3(256), 0, stream>>>(qarr, kx, vt, obs, Woq, boq,
                                                      varb, rtb, attnout);
    gemm_mfma<64, false><<<dim3(4, 96), dim3(256), 0, stream>>>(
        attnout, WoT, bo, out, nullptr, nullptr, nullptr);
}